// Round 20
// baseline (1649.675 us; speedup 1.0000x reference)
//
#include <hip/hip_runtime.h>
#include <hip/hip_bf16.h>

// Fused window cross-attention, MI355X gfx950. fp32 in, fp32 out.
// Round 20: PERSISTENT blocks — 256 blocks (1/CU), each processes 8
// x-consecutive windows of one batch. Round-19 4-region LDS schedule with
// rotating regions; next window's Xa/Xb are loaded during ph5/ph6 into the
// regions freed at b4/b5 (K and P), hiding HBM staging latency and removing
// 7 of 8 per-CU pipeline drains. 512 thr, 128KB LDS, cap 256 VGPR (512,1).
//   regions: RA/RD: Xa->V^T / K (parity-swapped); RB: Xb->P; RC: Q->O
// Weights pre-packed to bf16 MFMA fragment order (round-6 win).

typedef __bf16 bf16x8 __attribute__((ext_vector_type(8)));
typedef float f32x4 __attribute__((ext_vector_type(4)));
typedef unsigned short u16;
typedef unsigned short u16x8 __attribute__((ext_vector_type(8)));

#define MFMA16(A, B, C) __builtin_amdgcn_mfma_f32_16x16x32_bf16((A), (B), (C), 0, 0, 0)

__device__ __forceinline__ int swzA(int t, int byteInRow) {        // rows of 512B ([64][256] bf16)
    return (t << 9) + (byteInRow ^ ((((t & 7) ^ (t >> 3)) & 7) << 4));
}
__device__ __forceinline__ int swzB(int r, int byteInRow) {        // rows of 128B ([*][64] bf16)
    return (r << 7) + (byteInRow ^ ((((r & 7) ^ (r >> 3)) & 7) << 4));
}

// ---------------- prep: pack weights into fragment order ----------------
__global__ __launch_bounds__(256) void pack_weights(
    const float* __restrict__ Wq, const float* __restrict__ Wk,
    const float* __restrict__ Wv, const float* __restrict__ Wo,
    __bf16* __restrict__ pk)
{
    int gid = blockIdx.x * 256 + threadIdx.x;   // 0..32767
    int m = gid >> 13;
    int f = gid & 8191;
    const float* W = (m == 0) ? Wq : (m == 1) ? Wk : (m == 2) ? Wv : Wo;
    int q  = f >> 11;
    int kk = (f >> 8) & 7;
    int t16 = (f >> 6) & 3;
    int l  = f & 63;
    int row = (q << 6) + (t16 << 4) + (l & 15);
    int col = (kk << 5) + ((l >> 4) << 3);
    const float* s = W + row * 256 + col;
    f32x4 a = *(const f32x4*)s;
    f32x4 b = *(const f32x4*)(s + 4);
    bf16x8 r;
    r[0] = (__bf16)a[0]; r[1] = (__bf16)a[1]; r[2] = (__bf16)a[2]; r[3] = (__bf16)a[3];
    r[4] = (__bf16)b[0]; r[5] = (__bf16)b[1]; r[6] = (__bf16)b[2]; r[7] = (__bf16)b[3];
    *(bf16x8*)(pk + (size_t)gid * 8) = r;
}

__device__ __forceinline__ bf16x8 loadWP(const __bf16* __restrict__ pk,
                                         int q, int kk, int t16, int l) {
    return *(const bf16x8*)(pk + ((((q << 3) + kk) << 2) + t16) * 512 + (l << 3));
}

// issue the 8 vector loads for one tensor's 8x8 window tile (values kept in regs)
__device__ __forceinline__ void stage_load(const float* __restrict__ src,
                                           int b, int ybase, int xbase, int tid,
                                           f32x4 v[8]) {
    #pragma unroll
    for (int it = 0; it < 4; ++it) {
        int idx = (it << 9) + tid;              // (c, ty)
        int c  = idx >> 3;
        int ty = idx & 7;
        const float* gp = src + ((((size_t)b * 256 + c) * 128 + ybase + ty) * 128 + xbase);
        v[it * 2]     = *(const f32x4*)gp;
        v[it * 2 + 1] = *(const f32x4*)(gp + 4);
    }
}
// write staged values (fp32 regs -> bf16 swizzled LDS)
__device__ __forceinline__ void stage_write(char* dst, int tid, const f32x4 v[8]) {
    #pragma unroll
    for (int it = 0; it < 4; ++it) {
        int idx = (it << 9) + tid;
        int c  = idx >> 3;
        int ty = idx & 7;
        #pragma unroll
        for (int tx = 0; tx < 4; ++tx) {
            *(__bf16*)(dst + swzA((ty << 3) + tx,     c << 1)) = (__bf16)v[it * 2][tx];
            *(__bf16*)(dst + swzA((ty << 3) + 4 + tx, c << 1)) = (__bf16)v[it * 2 + 1][tx];
        }
    }
}

__global__ __launch_bounds__(512, 1) void wca_fused(
    const float* __restrict__ fa, const float* __restrict__ fb,
    const __bf16* __restrict__ WPq, const float* __restrict__ bq,
    const __bf16* __restrict__ WPk, const float* __restrict__ bk,
    const __bf16* __restrict__ WPv, const float* __restrict__ bv,
    const __bf16* __restrict__ WPo, const float* __restrict__ bo,
    float* __restrict__ outg, float* __restrict__ attng)
{
    __shared__ __attribute__((aligned(16))) char S[131072];
    char* const RA = S;              // parity0: Xa->V^T ; parity1: K
    char* const RB = S + 32768;      // Xb -> P (always)
    char* const RC = S + 65536;      // Q -> O (always)
    char* const RD = S + 98304;      // parity0: K ; parity1: Xa->V^T

    const int tid  = threadIdx.x;
    const int l    = tid & 63;
    const int wid  = tid >> 6;      // wave 0..7
    const int lrow = l & 15;
    const int kg   = l >> 4;
    const int q    = wid & 3;       // head / 64-col group
    const int th   = wid >> 2;      // 32-token half (0/1)

    const int bid  = blockIdx.x;    // 0..255
    const int b    = bid & 7;       // batch -> XCD
    const int s    = bid >> 3;      // 0..31
    const int wy   = s >> 1;
    const int wxh  = (s & 1) << 3;  // window-x base of this block's strip
    const int ybase = wy << 3;

    // ---------------- ph0: stage window 0 ----------------
    {
        f32x4 va[8], vb2[8];
        stage_load(fa, b, ybase, wxh << 3, tid, va);
        stage_load(fb, b, ybase, wxh << 3, tid, vb2);
        stage_write(RA, tid, va);
        stage_write(RB, tid, vb2);
    }
    __syncthreads();

    #pragma unroll 1
    for (int i = 0; i < 8; ++i) {
        char* const Xa_r = (i & 1) ? RD : RA;
        char* const K_r  = (i & 1) ? RA : RD;
        const int wx    = wxh + i;
        const int xbase = wx << 3;
        const int win   = (b << 8) + (wy << 4) + wx;
        const bool more = (i < 7);

        // ---------------- ph2: Q = Xa*Wq^T -> RC ; K = Xb*Wk^T -> K_r ----------------
        {
            f32x4 qacc[2][4] = {};
            #pragma unroll
            for (int kk = 0; kk < 8; ++kk) {
                int c0 = (kk << 5) + (kg << 3);
                bf16x8 a0 = *(const bf16x8*)(Xa_r + swzA((th << 5) + lrow,      c0 << 1));
                bf16x8 a1 = *(const bf16x8*)(Xa_r + swzA((th << 5) + 16 + lrow, c0 << 1));
                #pragma unroll
                for (int nt = 0; nt < 4; ++nt) {
                    bf16x8 bb = loadWP(WPq, q, kk, nt, l);
                    qacc[0][nt] = MFMA16(a0, bb, qacc[0][nt]);
                    qacc[1][nt] = MFMA16(a1, bb, qacc[1][nt]);
                }
            }
            #pragma unroll
            for (int mt = 0; mt < 2; ++mt) {
                #pragma unroll
                for (int nt = 0; nt < 4; ++nt) {
                    int co = (q << 6) + (nt << 4) + lrow;
                    float bi = bq[co];
                    #pragma unroll
                    for (int r = 0; r < 4; ++r) {
                        int t = (th << 5) + (mt << 4) + (kg << 2) + r;
                        *(__bf16*)(RC + swzA(t, co << 1)) = (__bf16)(qacc[mt][nt][r] + bi);
                    }
                }
            }
            f32x4 kacc[2][4] = {};
            #pragma unroll
            for (int kk = 0; kk < 8; ++kk) {
                int c0 = (kk << 5) + (kg << 3);
                bf16x8 a0 = *(const bf16x8*)(RB + swzA((th << 5) + lrow,      c0 << 1));
                bf16x8 a1 = *(const bf16x8*)(RB + swzA((th << 5) + 16 + lrow, c0 << 1));
                #pragma unroll
                for (int nt = 0; nt < 4; ++nt) {
                    bf16x8 bb = loadWP(WPk, q, kk, nt, l);
                    kacc[0][nt] = MFMA16(a0, bb, kacc[0][nt]);
                    kacc[1][nt] = MFMA16(a1, bb, kacc[1][nt]);
                }
            }
            #pragma unroll
            for (int mt = 0; mt < 2; ++mt) {
                #pragma unroll
                for (int nt = 0; nt < 4; ++nt) {
                    int co = (q << 6) + (nt << 4) + lrow;
                    float bi = bk[co];
                    #pragma unroll
                    for (int r = 0; r < 4; ++r) {
                        int t = (th << 5) + (mt << 4) + (kg << 2) + r;
                        *(__bf16*)(K_r + swzA(t, co << 1)) = (__bf16)(kacc[mt][nt][r] + bi);
                    }
                }
            }
        }
        __syncthreads();   // b2 (Xa reads done; Q,K visible)

        // ---------------- ph3: V^T = Wv * Xb^T -> Xa_r ----------------
        {
            f32x4 vacc[4][2] = {};
            #pragma unroll
            for (int kk = 0; kk < 8; ++kk) {
                int c0 = (kk << 5) + (kg << 3);
                bf16x8 bx0 = *(const bf16x8*)(RB + swzA((th << 5) + lrow,      c0 << 1));
                bf16x8 bx1 = *(const bf16x8*)(RB + swzA((th << 5) + 16 + lrow, c0 << 1));
                #pragma unroll
                for (int mt = 0; mt < 4; ++mt) {
                    bf16x8 aw = loadWP(WPv, q, kk, mt, l);
                    vacc[mt][0] = MFMA16(aw, bx0, vacc[mt][0]);
                    vacc[mt][1] = MFMA16(aw, bx1, vacc[mt][1]);
                }
            }
            #pragma unroll
            for (int mt = 0; mt < 4; ++mt) {
                #pragma unroll
                for (int r = 0; r < 4; ++r) {
                    int vc = (q << 6) + (mt << 4) + (kg << 2) + r;   // channel row of V^T
                    float bi = bv[vc];
                    #pragma unroll
                    for (int nt = 0; nt < 2; ++nt) {
                        int t = (th << 5) + (nt << 4) + lrow;
                        *(__bf16*)(Xa_r + swzB(vc, t << 1)) = (__bf16)(vacc[mt][nt][r] + bi);
                    }
                }
            }
        }
        __syncthreads();   // b3 (Xb reads done; V^T visible)

        // ---------------- ph4: S = Q_h K_h^T, softmax -> P (RB) ----------------
        {
            const int h = q;
            f32x4 sacc[2][4] = {};
            #pragma unroll
            for (int kk = 0; kk < 2; ++kk) {
                int c0 = (h << 6) + (kk << 5) + (kg << 3);
                bf16x8 a0 = *(const bf16x8*)(RC + swzA((th << 5) + lrow,      c0 << 1));
                bf16x8 a1 = *(const bf16x8*)(RC + swzA((th << 5) + 16 + lrow, c0 << 1));
                #pragma unroll
                for (int nt = 0; nt < 4; ++nt) {
                    bf16x8 kb = *(const bf16x8*)(K_r + swzA((nt << 4) + lrow, c0 << 1));
                    sacc[0][nt] = MFMA16(a0, kb, sacc[0][nt]);
                    sacc[1][nt] = MFMA16(a1, kb, sacc[1][nt]);
                }
            }
            const float CS = 0.125f * 1.44269504f;
            char* pb = RB + (h << 13);
            #pragma unroll
            for (int mt = 0; mt < 2; ++mt) {
                #pragma unroll
                for (int r = 0; r < 4; ++r) {
                    float mx = fmaxf(fmaxf(sacc[mt][0][r], sacc[mt][1][r]),
                                     fmaxf(sacc[mt][2][r], sacc[mt][3][r]));
                    mx = fmaxf(mx, __shfl_xor(mx, 1));
                    mx = fmaxf(mx, __shfl_xor(mx, 2));
                    mx = fmaxf(mx, __shfl_xor(mx, 4));
                    mx = fmaxf(mx, __shfl_xor(mx, 8));
                    float p0 = exp2f((sacc[mt][0][r] - mx) * CS);
                    float p1 = exp2f((sacc[mt][1][r] - mx) * CS);
                    float p2 = exp2f((sacc[mt][2][r] - mx) * CS);
                    float p3 = exp2f((sacc[mt][3][r] - mx) * CS);
                    float sm = (p0 + p1) + (p2 + p3);
                    sm += __shfl_xor(sm, 1);
                    sm += __shfl_xor(sm, 2);
                    sm += __shfl_xor(sm, 4);
                    sm += __shfl_xor(sm, 8);
                    float inv = 1.0f / sm;
                    int ii = (th << 5) + (mt << 4) + (kg << 2) + r;
                    *(__bf16*)(pb + swzB(ii, ((0 << 4) + lrow) << 1)) = (__bf16)(p0 * inv);
                    *(__bf16*)(pb + swzB(ii, ((1 << 4) + lrow) << 1)) = (__bf16)(p1 * inv);
                    *(__bf16*)(pb + swzB(ii, ((2 << 4) + lrow) << 1)) = (__bf16)(p2 * inv);
                    *(__bf16*)(pb + swzB(ii, ((3 << 4) + lrow) << 1)) = (__bf16)(p3 * inv);
                }
            }
        }
        __syncthreads();   // b4 (Q/K reads done -> RC, K_r free; P visible)

        // ---------------- ph5: [issue next Xa] ; O = P*V -> RC ; attn copy ; [Xa -> K_r] ----------------
        {
            f32x4 stg[8];
            if (more) stage_load(fa, b, ybase, (wx + 1) << 3, tid, stg);
            const int h = q;
            f32x4 o[2][4] = {};
            #pragma unroll
            for (int kk = 0; kk < 2; ++kk) {
                int j0 = (kk << 5) + (kg << 3);
                bf16x8 a0 = *(const bf16x8*)(RB + (h << 13) + swzB((th << 5) + lrow,      j0 << 1));
                bf16x8 a1 = *(const bf16x8*)(RB + (h << 13) + swzB((th << 5) + 16 + lrow, j0 << 1));
                #pragma unroll
                for (int dt = 0; dt < 4; ++dt) {
                    bf16x8 vb = *(const bf16x8*)(Xa_r + swzB((h << 6) + (dt << 4) + lrow, j0 << 1));
                    o[0][dt] = MFMA16(a0, vb, o[0][dt]);
                    o[1][dt] = MFMA16(a1, vb, o[1][dt]);
                }
            }
            #pragma unroll
            for (int mt = 0; mt < 2; ++mt) {
                #pragma unroll
                for (int dt = 0; dt < 4; ++dt) {
                    #pragma unroll
                    for (int r = 0; r < 4; ++r) {
                        int t = (th << 5) + (mt << 4) + (kg << 2) + r;
                        int c = (h << 6) + (dt << 4) + lrow;
                        *(__bf16*)(RC + swzA(t, c << 1)) = (__bf16)o[mt][dt][r];
                    }
                }
            }
            // attn: P (LDS bf16) -> global fp32, 32B per lane fully coalesced
            #pragma unroll
            for (int it = 0; it < 4; ++it) {
                int idx = (it << 9) + tid;                 // 0..2047
                int h2 = idx >> 9;
                int i2 = (idx >> 3) & 63;
                int jb = (idx & 7) << 3;
                u16x8 v = *(const u16x8*)(RB + (h2 << 13) + swzB(i2, jb << 1));
                float* dp = attng + ((((size_t)(win << 2) + h2) << 6) + i2) * 64 + jb;
                f32x4 o0, o1;
                #pragma unroll
                for (int e = 0; e < 4; ++e) {
                    union { unsigned u; float f; } c0; c0.u = (unsigned)v[e] << 16;
                    union { unsigned u; float f; } c1; c1.u = (unsigned)v[4 + e] << 16;
                    o0[e] = c0.f; o1[e] = c1.f;
                }
                *(f32x4*)dp = o0;
                *(f32x4*)(dp + 4) = o1;
            }
            if (more) stage_write(K_r, tid, stg);   // next window's Xa (K dead since b4)
        }
        __syncthreads();   // b5 (P reads done; O + staged Xa visible)

        // ---------------- ph6: [issue next Xb] ; Out^T = Wo*O^T -> global ; [Xb -> RB] ----------------
        {
            f32x4 stg[8];
            if (more) stage_load(fb, b, ybase, (wx + 1) << 3, tid, stg);
            f32x4 acc[4][2] = {};
            #pragma unroll
            for (int kk = 0; kk < 8; ++kk) {
                int k0 = (kk << 5) + (kg << 3);
                bf16x8 b0 = *(const bf16x8*)(RC + swzA((th << 5) + lrow,      k0 << 1));
                bf16x8 b1 = *(const bf16x8*)(RC + swzA((th << 5) + 16 + lrow, k0 << 1));
                #pragma unroll
                for (int mt = 0; mt < 4; ++mt) {
                    bf16x8 aw = loadWP(WPo, q, kk, mt, l);
                    acc[mt][0] = MFMA16(aw, b0, acc[mt][0]);
                    acc[mt][1] = MFMA16(aw, b1, acc[mt][1]);
                }
            }
            #pragma unroll
            for (int mt = 0; mt < 4; ++mt) {
                #pragma unroll
                for (int r = 0; r < 4; ++r) {
                    int c = (q << 6) + (mt << 4) + (kg << 2) + r;
                    float bi = bo[c];
                    #pragma unroll
                    for (int nt = 0; nt < 2; ++nt) {
                        int t = (th << 5) + (nt << 4) + lrow;
                        int y = ybase + (t >> 3);
                        int x = xbase + (t & 7);
                        size_t off = (((size_t)b * 256 + c) * 128 + y) * 128 + x;
                        outg[off] = acc[mt][nt][r] + bi;
                    }
                }
            }
            if (more) stage_write(RB, tid, stg);    // next window's Xb (P dead since b5)
        }
        __syncthreads();   // b6 (O reads done; staged Xb visible) -> next window
    }
}

extern "C" void kernel_launch(void* const* d_in, const int* in_sizes, int n_in,
                              void* d_out, int out_size, void* d_ws, size_t ws_size,
                              hipStream_t stream) {
    (void)in_sizes; (void)n_in; (void)ws_size; (void)out_size;
    const float* fa = (const float*)d_in[0];
    const float* fb = (const float*)d_in[1];
    const float* Wq = (const float*)d_in[2];
    const float* bq = (const float*)d_in[3];
    const float* Wk = (const float*)d_in[4];
    const float* bk = (const float*)d_in[5];
    const float* Wv = (const float*)d_in[6];
    const float* bv = (const float*)d_in[7];
    const float* Wo = (const float*)d_in[8];
    const float* bo = (const float*)d_in[9];
    float* outg  = (float*)d_out;
    float* attng = outg + (size_t)8 * 256 * 128 * 128;   // out first, then attn (fp32)

    __bf16* pk = (__bf16*)d_ws;                          // 4 x 128KB packed weights
    const __bf16* WPq = pk;
    const __bf16* WPk = pk + 65536;
    const __bf16* WPv = pk + 131072;
    const __bf16* WPo = pk + 196608;

    pack_weights<<<dim3(128), dim3(256), 0, stream>>>(Wq, Wk, Wv, Wo, pk);
    wca_fused<<<dim3(256), dim3(512), 0, stream>>>(
        fa, fb, WPq, bq, WPk, bk, WPv, bv, WPo, bo, outg, attng);
}

// Round 21
// 417.803 us; speedup vs baseline: 3.9485x; 3.9485x over previous
//
#include <hip/hip_runtime.h>
#include <hip/hip_bf16.h>

// Fused window cross-attention, MI355X gfx950. fp32 in, fp32 out.
// Round 21: round-11 body (64KB LDS, clean traffic, 308us) +
// __attribute__((amdgpu_num_vgpr(112))): direct VGPR target. Ledger: clean
// needs ~112-128 regs; 2-blocks/CU residency needs <128 (r11: VGPR=128 ->
// 1 block; 4x128=512 exactly doesn't fit the file). 112x4=448<=512 -> 2
// blocks expected. r19 proved a near-identical body compiles clean at 112.
// R1(32KB): Xa -> Q -> V^T -> O ; R2(32KB): Xb -> K -> P.

typedef __bf16 bf16x8 __attribute__((ext_vector_type(8)));
typedef float f32x4 __attribute__((ext_vector_type(4)));
typedef unsigned short u16;
typedef unsigned short u16x8 __attribute__((ext_vector_type(8)));

#define MFMA16(A, B, C) __builtin_amdgcn_mfma_f32_16x16x32_bf16((A), (B), (C), 0, 0, 0)

__device__ __forceinline__ int swzA(int t, int byteInRow) {        // rows of 512B ([64][256] bf16)
    return (t << 9) + (byteInRow ^ ((((t & 7) ^ (t >> 3)) & 7) << 4));
}
__device__ __forceinline__ int swzB(int r, int byteInRow) {        // rows of 128B ([*][64] bf16)
    return (r << 7) + (byteInRow ^ ((((r & 7) ^ (r >> 3)) & 7) << 4));
}
__device__ __forceinline__ u16 bfbits(float x) {
    __bf16 h = (__bf16)x;
    return *(u16*)&h;
}

// ---------------- prep: pack weights into fragment order ----------------
__global__ __launch_bounds__(256) void pack_weights(
    const float* __restrict__ Wq, const float* __restrict__ Wk,
    const float* __restrict__ Wv, const float* __restrict__ Wo,
    __bf16* __restrict__ pk)
{
    int gid = blockIdx.x * 256 + threadIdx.x;   // 0..32767
    int m = gid >> 13;
    int f = gid & 8191;
    const float* W = (m == 0) ? Wq : (m == 1) ? Wk : (m == 2) ? Wv : Wo;
    int q  = f >> 11;
    int kk = (f >> 8) & 7;
    int t16 = (f >> 6) & 3;
    int l  = f & 63;
    int row = (q << 6) + (t16 << 4) + (l & 15);
    int col = (kk << 5) + ((l >> 4) << 3);
    const float* s = W + row * 256 + col;
    f32x4 a = *(const f32x4*)s;
    f32x4 b = *(const f32x4*)(s + 4);
    bf16x8 r;
    r[0] = (__bf16)a[0]; r[1] = (__bf16)a[1]; r[2] = (__bf16)a[2]; r[3] = (__bf16)a[3];
    r[4] = (__bf16)b[0]; r[5] = (__bf16)b[1]; r[6] = (__bf16)b[2]; r[7] = (__bf16)b[3];
    *(bf16x8*)(pk + (size_t)gid * 8) = r;
}

__device__ __forceinline__ bf16x8 loadWP(const __bf16* __restrict__ pk,
                                         int q, int kk, int t16, int l) {
    return *(const bf16x8*)(pk + ((((q << 3) + kk) << 2) + t16) * 512 + (l << 3));
}

__global__ __launch_bounds__(512, 2) __attribute__((amdgpu_num_vgpr(112)))
void wca_fused(
    const float* __restrict__ fa, const float* __restrict__ fb,
    const __bf16* __restrict__ WPq, const float* __restrict__ bq,
    const __bf16* __restrict__ WPk, const float* __restrict__ bk,
    const __bf16* __restrict__ WPv, const float* __restrict__ bv,
    const __bf16* __restrict__ WPo, const float* __restrict__ bo,
    float* __restrict__ outg, float* __restrict__ attng)
{
    __shared__ __attribute__((aligned(16))) char S[65536];
    char* const R1 = S;              // Xa -> Q [64][256] -> V^T [256][64] -> O [64][256]
    char* const R2 = S + 32768;      // Xb -> K [64][256] -> P [4][64][64]

    const int tid  = threadIdx.x;
    const int l    = tid & 63;
    const int wid  = tid >> 6;      // wave 0..7
    const int lrow = l & 15;
    const int kg   = l >> 4;
    const int q    = wid & 3;       // 64-wide output chunk / head id
    const int th   = wid >> 2;      // token half (0/1)

    const int wgid = blockIdx.x;
    const int win  = ((wgid & 7) << 8) | (wgid >> 3);
    const int b    = win >> 8;
    const int wy   = (win >> 4) & 15;
    const int wx   = win & 15;
    const int ybase = wy << 3, xbase = wx << 3;

    // ---------------- ph1: stage Xa -> R1, Xb -> R2 ----------------
    {
        #pragma unroll
        for (int f = 0; f < 2; ++f) {
            const float* src = f ? fb : fa;
            char* dst = f ? R2 : R1;
            #pragma unroll
            for (int it = 0; it < 4; ++it) {
                int idx = (it << 9) + tid;          // 0..2047 = (c, ty)
                int c  = idx >> 3;
                int ty = idx & 7;
                const float* gp = src + ((((size_t)b * 256 + c) * 128 + ybase + ty) * 128 + xbase);
                f32x4 v0 = *(const f32x4*)gp;
                f32x4 v1 = *(const f32x4*)(gp + 4);
                #pragma unroll
                for (int tx = 0; tx < 4; ++tx) {
                    *(__bf16*)(dst + swzA((ty << 3) + tx,     c << 1)) = (__bf16)v0[tx];
                    *(__bf16*)(dst + swzA((ty << 3) + 4 + tx, c << 1)) = (__bf16)v1[tx];
                }
            }
        }
    }
    __syncthreads();   // b1

    // ---------------- ph2: Q = Xa*Wq^T (regs) ----------------
    f32x4 qacc[2][4] = {};
    {
        #pragma unroll
        for (int kk = 0; kk < 8; ++kk) {
            int c0 = (kk << 5) + (kg << 3);
            bf16x8 a0 = *(const bf16x8*)(R1 + swzA((th << 5) + lrow,      c0 << 1));
            bf16x8 a1 = *(const bf16x8*)(R1 + swzA((th << 5) + 16 + lrow, c0 << 1));
            #pragma unroll
            for (int nt = 0; nt < 4; ++nt) {
                bf16x8 bb = loadWP(WPq, q, kk, nt, l);
                qacc[0][nt] = MFMA16(a0, bb, qacc[0][nt]);
                qacc[1][nt] = MFMA16(a1, bb, qacc[1][nt]);
            }
        }
    }
    __syncthreads();   // b2 (all Xa reads done)

    // ---------------- ph3: Q -> R1 ; K,V^T = f(Xb) -> regs (bf16-packed) ----------------
    unsigned kpk[16], vpk[16];
    {
        // Q write (over Xa)
        #pragma unroll
        for (int mt = 0; mt < 2; ++mt) {
            #pragma unroll
            for (int nt = 0; nt < 4; ++nt) {
                int co = (q << 6) + (nt << 4) + lrow;
                float bi = bq[co];
                #pragma unroll
                for (int r = 0; r < 4; ++r) {
                    int t = (th << 5) + (mt << 4) + (kg << 2) + r;
                    *(__bf16*)(R1 + swzA(t, co << 1)) = (__bf16)(qacc[mt][nt][r] + bi);
                }
            }
        }
        // K projection -> kacc -> kpk
        {
            f32x4 kacc[2][4] = {};
            #pragma unroll
            for (int kk = 0; kk < 8; ++kk) {
                int c0 = (kk << 5) + (kg << 3);
                bf16x8 a0 = *(const bf16x8*)(R2 + swzA((th << 5) + lrow,      c0 << 1));
                bf16x8 a1 = *(const bf16x8*)(R2 + swzA((th << 5) + 16 + lrow, c0 << 1));
                #pragma unroll
                for (int nt = 0; nt < 4; ++nt) {
                    bf16x8 bb = loadWP(WPk, q, kk, nt, l);
                    kacc[0][nt] = MFMA16(a0, bb, kacc[0][nt]);
                    kacc[1][nt] = MFMA16(a1, bb, kacc[1][nt]);
                }
            }
            #pragma unroll
            for (int mt = 0; mt < 2; ++mt) {
                #pragma unroll
                for (int nt = 0; nt < 4; ++nt) {
                    float bi = bk[(q << 6) + (nt << 4) + lrow];
                    kpk[(mt * 4 + nt) * 2 + 0] =
                        (unsigned)bfbits(kacc[mt][nt][0] + bi) |
                        ((unsigned)bfbits(kacc[mt][nt][1] + bi) << 16);
                    kpk[(mt * 4 + nt) * 2 + 1] =
                        (unsigned)bfbits(kacc[mt][nt][2] + bi) |
                        ((unsigned)bfbits(kacc[mt][nt][3] + bi) << 16);
                }
            }
        }
        // V^T projection -> vacc -> vpk
        {
            f32x4 vacc[4][2] = {};
            #pragma unroll
            for (int kk = 0; kk < 8; ++kk) {
                int c0 = (kk << 5) + (kg << 3);
                bf16x8 bx0 = *(const bf16x8*)(R2 + swzA((th << 5) + lrow,      c0 << 1));
                bf16x8 bx1 = *(const bf16x8*)(R2 + swzA((th << 5) + 16 + lrow, c0 << 1));
                #pragma unroll
                for (int mt = 0; mt < 4; ++mt) {
                    bf16x8 aw = loadWP(WPv, q, kk, mt, l);
                    vacc[mt][0] = MFMA16(aw, bx0, vacc[mt][0]);
                    vacc[mt][1] = MFMA16(aw, bx1, vacc[mt][1]);
                }
            }
            #pragma unroll
            for (int mt = 0; mt < 4; ++mt) {
                #pragma unroll
                for (int nt = 0; nt < 2; ++nt) {
                    u16 w0 = bfbits(vacc[mt][nt][0] + bv[(q << 6) + (mt << 4) + (kg << 2) + 0]);
                    u16 w1 = bfbits(vacc[mt][nt][1] + bv[(q << 6) + (mt << 4) + (kg << 2) + 1]);
                    u16 w2 = bfbits(vacc[mt][nt][2] + bv[(q << 6) + (mt << 4) + (kg << 2) + 2]);
                    u16 w3 = bfbits(vacc[mt][nt][3] + bv[(q << 6) + (mt << 4) + (kg << 2) + 3]);
                    vpk[(mt * 2 + nt) * 2 + 0] = (unsigned)w0 | ((unsigned)w1 << 16);
                    vpk[(mt * 2 + nt) * 2 + 1] = (unsigned)w2 | ((unsigned)w3 << 16);
                }
            }
        }
    }
    __syncthreads();   // b3 (all Xb reads + Q writes done)

    // ---------------- ph4: K -> R2 (over Xb) ----------------
    {
        #pragma unroll
        for (int mt = 0; mt < 2; ++mt) {
            #pragma unroll
            for (int nt = 0; nt < 4; ++nt) {
                int co = (q << 6) + (nt << 4) + lrow;
                #pragma unroll
                for (int r = 0; r < 4; ++r) {
                    int t = (th << 5) + (mt << 4) + (kg << 2) + r;
                    u16 val = (u16)(kpk[(mt * 4 + nt) * 2 + (r >> 1)] >> ((r & 1) * 16));
                    *(u16*)(R2 + swzA(t, co << 1)) = val;
                }
            }
        }
    }
    __syncthreads();   // b4

    // ---------------- ph5: S = Q_h K_h^T, softmax -> ppk regs ----------------
    unsigned ppk[16];
    {
        const int h = q;
        f32x4 s[2][4] = {};
        #pragma unroll
        for (int kk = 0; kk < 2; ++kk) {
            int c0 = (h << 6) + (kk << 5) + (kg << 3);
            bf16x8 a0 = *(const bf16x8*)(R1 + swzA((th << 5) + lrow,      c0 << 1));
            bf16x8 a1 = *(const bf16x8*)(R1 + swzA((th << 5) + 16 + lrow, c0 << 1));
            #pragma unroll
            for (int nt = 0; nt < 4; ++nt) {
                bf16x8 kb = *(const bf16x8*)(R2 + swzA((nt << 4) + lrow, c0 << 1));
                s[0][nt] = MFMA16(a0, kb, s[0][nt]);
                s[1][nt] = MFMA16(a1, kb, s[1][nt]);
            }
        }
        const float CS = 0.125f * 1.44269504f;
        #pragma unroll
        for (int mt = 0; mt < 2; ++mt) {
            #pragma unroll
            for (int r = 0; r < 4; ++r) {
                float mx = fmaxf(fmaxf(s[mt][0][r], s[mt][1][r]),
                                 fmaxf(s[mt][2][r], s[mt][3][r]));
                mx = fmaxf(mx, __shfl_xor(mx, 1));
                mx = fmaxf(mx, __shfl_xor(mx, 2));
                mx = fmaxf(mx, __shfl_xor(mx, 4));
                mx = fmaxf(mx, __shfl_xor(mx, 8));
                float p0 = exp2f((s[mt][0][r] - mx) * CS);
                float p1 = exp2f((s[mt][1][r] - mx) * CS);
                float p2 = exp2f((s[mt][2][r] - mx) * CS);
                float p3 = exp2f((s[mt][3][r] - mx) * CS);
                float sm = (p0 + p1) + (p2 + p3);
                sm += __shfl_xor(sm, 1);
                sm += __shfl_xor(sm, 2);
                sm += __shfl_xor(sm, 4);
                sm += __shfl_xor(sm, 8);
                float inv = 1.0f / sm;
                p0 *= inv; p1 *= inv; p2 *= inv; p3 *= inv;
                ppk[(mt * 4 + r) * 2 + 0] = (unsigned)bfbits(p0) | ((unsigned)bfbits(p1) << 16);
                ppk[(mt * 4 + r) * 2 + 1] = (unsigned)bfbits(p2) | ((unsigned)bfbits(p3) << 16);
            }
        }
    }
    __syncthreads();   // b5 (all Q/K reads done)

    // ---------------- ph6: P -> R2 ([4][64][64]) ; V^T -> R1 ([256][64]) ----------------
    {
        const int h = q;
        #pragma unroll
        for (int mt = 0; mt < 2; ++mt) {
            #pragma unroll
            for (int r = 0; r < 4; ++r) {
                int i = (th << 5) + (mt << 4) + (kg << 2) + r;
                #pragma unroll
                for (int nt = 0; nt < 4; ++nt) {
                    u16 val = (u16)(ppk[(mt * 4 + r) * 2 + (nt >> 1)] >> ((nt & 1) * 16));
                    *(u16*)(R2 + (h << 13) + swzB(i, ((nt << 4) + lrow) << 1)) = val;
                }
            }
        }
        #pragma unroll
        for (int mt = 0; mt < 4; ++mt) {
            #pragma unroll
            for (int r = 0; r < 4; ++r) {
                int vc = (q << 6) + (mt << 4) + (kg << 2) + r;
                #pragma unroll
                for (int nt = 0; nt < 2; ++nt) {
                    int t = (th << 5) + (nt << 4) + lrow;
                    u16 val = (u16)(vpk[(mt * 2 + nt) * 2 + (r >> 1)] >> ((r & 1) * 16));
                    *(u16*)(R1 + swzB(vc, t << 1)) = val;
                }
            }
        }
    }
    __syncthreads();   // b6

    // ---------------- ph7: O = P * V (regs) + attn copy (LDS -> global, coalesced) ----------------
    f32x4 o[2][4] = {};
    {
        const int h = q;
        #pragma unroll
        for (int kk = 0; kk < 2; ++kk) {
            int j0 = (kk << 5) + (kg << 3);
            bf16x8 a0 = *(const bf16x8*)(R2 + (h << 13) + swzB((th << 5) + lrow,      j0 << 1));
            bf16x8 a1 = *(const bf16x8*)(R2 + (h << 13) + swzB((th << 5) + 16 + lrow, j0 << 1));
            #pragma unroll
            for (int dt = 0; dt < 4; ++dt) {
                bf16x8 vb = *(const bf16x8*)(R1 + swzB((h << 6) + (dt << 4) + lrow, j0 << 1));
                o[0][dt] = MFMA16(a0, vb, o[0][dt]);
                o[1][dt] = MFMA16(a1, vb, o[1][dt]);
            }
        }
        // attn: P (LDS bf16) -> global fp32, 32B per lane fully coalesced
        #pragma unroll
        for (int it = 0; it < 4; ++it) {
            int idx = (it << 9) + tid;                 // 0..2047
            int h2 = idx >> 9;
            int i2 = (idx >> 3) & 63;
            int jb = (idx & 7) << 3;
            u16x8 v = *(const u16x8*)(R2 + (h2 << 13) + swzB(i2, jb << 1));
            float* dp = attng + ((((size_t)(win << 2) + h2) << 6) + i2) * 64 + jb;
            f32x4 o0, o1;
            #pragma unroll
            for (int e = 0; e < 4; ++e) {
                union { unsigned u; float f; } c0; c0.u = (unsigned)v[e] << 16;
                union { unsigned u; float f; } c1; c1.u = (unsigned)v[4 + e] << 16;
                o0[e] = c0.f; o1[e] = c1.f;
            }
            *(f32x4*)dp = o0;
            *(f32x4*)(dp + 4) = o1;
        }
    }
    __syncthreads();   // b7 (all P/V reads done)

    // ---------------- ph8: O -> R1 ([64][256]) ----------------
    {
        const int h = q;
        #pragma unroll
        for (int mt = 0; mt < 2; ++mt) {
            #pragma unroll
            for (int dt = 0; dt < 4; ++dt) {
                #pragma unroll
                for (int r = 0; r < 4; ++r) {
                    int t = (th << 5) + (mt << 4) + (kg << 2) + r;
                    int c = (h << 6) + (dt << 4) + lrow;
                    *(__bf16*)(R1 + swzA(t, c << 1)) = (__bf16)o[mt][dt][r];
                }
            }
        }
    }
    __syncthreads();   // b8

    // ---------------- ph9: Out^T = Wo * O^T + bo -> global ----------------
    {
        f32x4 acc[4][2] = {};
        #pragma unroll
        for (int kk = 0; kk < 8; ++kk) {
            int k0 = (kk << 5) + (kg << 3);
            bf16x8 b0 = *(const bf16x8*)(R1 + swzA((th << 5) + lrow,      k0 << 1));
            bf16x8 b1 = *(const bf16x8*)(R1 + swzA((th << 5) + 16 + lrow, k0 << 1));
            #pragma unroll
            for (int mt = 0; mt < 4; ++mt) {
                bf16x8 aw = loadWP(WPo, q, kk, mt, l);
                acc[mt][0] = MFMA16(aw, b0, acc[mt][0]);
                acc[mt][1] = MFMA16(aw, b1, acc[mt][1]);
            }
        }
        #pragma unroll
        for (int mt = 0; mt < 4; ++mt) {
            #pragma unroll
            for (int r = 0; r < 4; ++r) {
                int c = (q << 6) + (mt << 4) + (kg << 2) + r;
                float bi = bo[c];
                #pragma unroll
                for (int nt = 0; nt < 2; ++nt) {
                    int t = (th << 5) + (nt << 4) + lrow;
                    int y = ybase + (t >> 3);
                    int x = xbase + (t & 7);
                    size_t off = (((size_t)b * 256 + c) * 128 + y) * 128 + x;
                    outg[off] = acc[mt][nt][r] + bi;
                }
            }
        }
    }
}

extern "C" void kernel_launch(void* const* d_in, const int* in_sizes, int n_in,
                              void* d_out, int out_size, void* d_ws, size_t ws_size,
                              hipStream_t stream) {
    (void)in_sizes; (void)n_in; (void)ws_size; (void)out_size;
    const float* fa = (const float*)d_in[0];
    const float* fb = (const float*)d_in[1];
    const float* Wq = (const float*)d_in[2];
    const float* bq = (const float*)d_in[3];
    const float* Wk = (const float*)d_in[4];
    const float* bk = (const float*)d_in[5];
    const float* Wv = (const float*)d_in[6];
    const float* bv = (const float*)d_in[7];
    const float* Wo = (const float*)d_in[8];
    const float* bo = (const float*)d_in[9];
    float* outg  = (float*)d_out;
    float* attng = outg + (size_t)8 * 256 * 128 * 128;   // out first, then attn (fp32)

    __bf16* pk = (__bf16*)d_ws;                          // 4 x 128KB packed weights
    const __bf16* WPq = pk;
    const __bf16* WPk = pk + 65536;
    const __bf16* WPv = pk + 131072;
    const __bf16* WPo = pk + 196608;

    pack_weights<<<dim3(128), dim3(256), 0, stream>>>(Wq, Wk, Wv, Wo, pk);
    wca_fused<<<dim3(2048), dim3(512), 0, stream>>>(
        fa, fb, WPq, bq, WPk, bk, WPv, bv, WPo, bo, outg, attng);
}

// Round 22
// 307.764 us; speedup vs baseline: 5.3602x; 1.3575x over previous
//
#include <hip/hip_runtime.h>
#include <hip/hip_bf16.h>

// Fused window cross-attention, MI355X gfx950. fp32 in, fp32 out.
// Round 22: exact round-11 body (best clean config: 308us, VGPR 128, 64KB LDS,
// 1 block/CU) + ONE change: the attn copy (134MB of stores) moved from ph7
// (where __syncthreads forced a vmcnt(0) drain of all 8 stores/thread) to the
// KERNEL TAIL after the out stores, with no barrier after it. Stores fly
// during block exit and overlap the next block's staging.
// R1(32KB): Xa -> Q -> V^T -> O ; R2(32KB): Xb -> K -> P (P live to the end).

typedef __bf16 bf16x8 __attribute__((ext_vector_type(8)));
typedef float f32x4 __attribute__((ext_vector_type(4)));
typedef unsigned short u16;
typedef unsigned short u16x8 __attribute__((ext_vector_type(8)));

#define MFMA16(A, B, C) __builtin_amdgcn_mfma_f32_16x16x32_bf16((A), (B), (C), 0, 0, 0)

__device__ __forceinline__ int swzA(int t, int byteInRow) {        // rows of 512B ([64][256] bf16)
    return (t << 9) + (byteInRow ^ ((((t & 7) ^ (t >> 3)) & 7) << 4));
}
__device__ __forceinline__ int swzB(int r, int byteInRow) {        // rows of 128B ([*][64] bf16)
    return (r << 7) + (byteInRow ^ ((((r & 7) ^ (r >> 3)) & 7) << 4));
}
__device__ __forceinline__ u16 bfbits(float x) {
    __bf16 h = (__bf16)x;
    return *(u16*)&h;
}

// ---------------- prep: pack weights into fragment order ----------------
__global__ __launch_bounds__(256) void pack_weights(
    const float* __restrict__ Wq, const float* __restrict__ Wk,
    const float* __restrict__ Wv, const float* __restrict__ Wo,
    __bf16* __restrict__ pk)
{
    int gid = blockIdx.x * 256 + threadIdx.x;   // 0..32767
    int m = gid >> 13;
    int f = gid & 8191;
    const float* W = (m == 0) ? Wq : (m == 1) ? Wk : (m == 2) ? Wv : Wo;
    int q  = f >> 11;
    int kk = (f >> 8) & 7;
    int t16 = (f >> 6) & 3;
    int l  = f & 63;
    int row = (q << 6) + (t16 << 4) + (l & 15);
    int col = (kk << 5) + ((l >> 4) << 3);
    const float* s = W + row * 256 + col;
    f32x4 a = *(const f32x4*)s;
    f32x4 b = *(const f32x4*)(s + 4);
    bf16x8 r;
    r[0] = (__bf16)a[0]; r[1] = (__bf16)a[1]; r[2] = (__bf16)a[2]; r[3] = (__bf16)a[3];
    r[4] = (__bf16)b[0]; r[5] = (__bf16)b[1]; r[6] = (__bf16)b[2]; r[7] = (__bf16)b[3];
    *(bf16x8*)(pk + (size_t)gid * 8) = r;
}

__device__ __forceinline__ bf16x8 loadWP(const __bf16* __restrict__ pk,
                                         int q, int kk, int t16, int l) {
    return *(const bf16x8*)(pk + ((((q << 3) + kk) << 2) + t16) * 512 + (l << 3));
}

__global__ __launch_bounds__(512, 2) void wca_fused(
    const float* __restrict__ fa, const float* __restrict__ fb,
    const __bf16* __restrict__ WPq, const float* __restrict__ bq,
    const __bf16* __restrict__ WPk, const float* __restrict__ bk,
    const __bf16* __restrict__ WPv, const float* __restrict__ bv,
    const __bf16* __restrict__ WPo, const float* __restrict__ bo,
    float* __restrict__ outg, float* __restrict__ attng)
{
    __shared__ __attribute__((aligned(16))) char S[65536];
    char* const R1 = S;              // Xa -> Q [64][256] -> V^T [256][64] -> O [64][256]
    char* const R2 = S + 32768;      // Xb -> K [64][256] -> P [4][64][64] (P live to end)

    const int tid  = threadIdx.x;
    const int l    = tid & 63;
    const int wid  = tid >> 6;      // wave 0..7
    const int lrow = l & 15;
    const int kg   = l >> 4;
    const int q    = wid & 3;       // 64-wide output chunk / head id
    const int th   = wid >> 2;      // token half (0/1)

    const int wgid = blockIdx.x;
    const int win  = ((wgid & 7) << 8) | (wgid >> 3);
    const int b    = win >> 8;
    const int wy   = (win >> 4) & 15;
    const int wx   = win & 15;
    const int ybase = wy << 3, xbase = wx << 3;

    // ---------------- ph1: stage Xa -> R1, Xb -> R2 ----------------
    {
        #pragma unroll
        for (int f = 0; f < 2; ++f) {
            const float* src = f ? fb : fa;
            char* dst = f ? R2 : R1;
            #pragma unroll
            for (int it = 0; it < 4; ++it) {
                int idx = (it << 9) + tid;          // 0..2047 = (c, ty)
                int c  = idx >> 3;
                int ty = idx & 7;
                const float* gp = src + ((((size_t)b * 256 + c) * 128 + ybase + ty) * 128 + xbase);
                f32x4 v0 = *(const f32x4*)gp;
                f32x4 v1 = *(const f32x4*)(gp + 4);
                #pragma unroll
                for (int tx = 0; tx < 4; ++tx) {
                    *(__bf16*)(dst + swzA((ty << 3) + tx,     c << 1)) = (__bf16)v0[tx];
                    *(__bf16*)(dst + swzA((ty << 3) + 4 + tx, c << 1)) = (__bf16)v1[tx];
                }
            }
        }
    }
    __syncthreads();   // b1

    // ---------------- ph2: Q = Xa*Wq^T (regs) ----------------
    f32x4 qacc[2][4] = {};
    {
        #pragma unroll
        for (int kk = 0; kk < 8; ++kk) {
            int c0 = (kk << 5) + (kg << 3);
            bf16x8 a0 = *(const bf16x8*)(R1 + swzA((th << 5) + lrow,      c0 << 1));
            bf16x8 a1 = *(const bf16x8*)(R1 + swzA((th << 5) + 16 + lrow, c0 << 1));
            #pragma unroll
            for (int nt = 0; nt < 4; ++nt) {
                bf16x8 bb = loadWP(WPq, q, kk, nt, l);
                qacc[0][nt] = MFMA16(a0, bb, qacc[0][nt]);
                qacc[1][nt] = MFMA16(a1, bb, qacc[1][nt]);
            }
        }
    }
    __syncthreads();   // b2 (all Xa reads done)

    // ---------------- ph3: Q -> R1 ; K,V^T = f(Xb) -> regs (bf16-packed) ----------------
    unsigned kpk[16], vpk[16];
    {
        // Q write (over Xa)
        #pragma unroll
        for (int mt = 0; mt < 2; ++mt) {
            #pragma unroll
            for (int nt = 0; nt < 4; ++nt) {
                int co = (q << 6) + (nt << 4) + lrow;
                float bi = bq[co];
                #pragma unroll
                for (int r = 0; r < 4; ++r) {
                    int t = (th << 5) + (mt << 4) + (kg << 2) + r;
                    *(__bf16*)(R1 + swzA(t, co << 1)) = (__bf16)(qacc[mt][nt][r] + bi);
                }
            }
        }
        // K projection -> kacc -> kpk
        {
            f32x4 kacc[2][4] = {};
            #pragma unroll
            for (int kk = 0; kk < 8; ++kk) {
                int c0 = (kk << 5) + (kg << 3);
                bf16x8 a0 = *(const bf16x8*)(R2 + swzA((th << 5) + lrow,      c0 << 1));
                bf16x8 a1 = *(const bf16x8*)(R2 + swzA((th << 5) + 16 + lrow, c0 << 1));
                #pragma unroll
                for (int nt = 0; nt < 4; ++nt) {
                    bf16x8 bb = loadWP(WPk, q, kk, nt, l);
                    kacc[0][nt] = MFMA16(a0, bb, kacc[0][nt]);
                    kacc[1][nt] = MFMA16(a1, bb, kacc[1][nt]);
                }
            }
            #pragma unroll
            for (int mt = 0; mt < 2; ++mt) {
                #pragma unroll
                for (int nt = 0; nt < 4; ++nt) {
                    float bi = bk[(q << 6) + (nt << 4) + lrow];
                    kpk[(mt * 4 + nt) * 2 + 0] =
                        (unsigned)bfbits(kacc[mt][nt][0] + bi) |
                        ((unsigned)bfbits(kacc[mt][nt][1] + bi) << 16);
                    kpk[(mt * 4 + nt) * 2 + 1] =
                        (unsigned)bfbits(kacc[mt][nt][2] + bi) |
                        ((unsigned)bfbits(kacc[mt][nt][3] + bi) << 16);
                }
            }
        }
        // V^T projection -> vacc -> vpk
        {
            f32x4 vacc[4][2] = {};
            #pragma unroll
            for (int kk = 0; kk < 8; ++kk) {
                int c0 = (kk << 5) + (kg << 3);
                bf16x8 bx0 = *(const bf16x8*)(R2 + swzA((th << 5) + lrow,      c0 << 1));
                bf16x8 bx1 = *(const bf16x8*)(R2 + swzA((th << 5) + 16 + lrow, c0 << 1));
                #pragma unroll
                for (int mt = 0; mt < 4; ++mt) {
                    bf16x8 aw = loadWP(WPv, q, kk, mt, l);
                    vacc[mt][0] = MFMA16(aw, bx0, vacc[mt][0]);
                    vacc[mt][1] = MFMA16(aw, bx1, vacc[mt][1]);
                }
            }
            #pragma unroll
            for (int mt = 0; mt < 4; ++mt) {
                #pragma unroll
                for (int nt = 0; nt < 2; ++nt) {
                    u16 w0 = bfbits(vacc[mt][nt][0] + bv[(q << 6) + (mt << 4) + (kg << 2) + 0]);
                    u16 w1 = bfbits(vacc[mt][nt][1] + bv[(q << 6) + (mt << 4) + (kg << 2) + 1]);
                    u16 w2 = bfbits(vacc[mt][nt][2] + bv[(q << 6) + (mt << 4) + (kg << 2) + 2]);
                    u16 w3 = bfbits(vacc[mt][nt][3] + bv[(q << 6) + (mt << 4) + (kg << 2) + 3]);
                    vpk[(mt * 2 + nt) * 2 + 0] = (unsigned)w0 | ((unsigned)w1 << 16);
                    vpk[(mt * 2 + nt) * 2 + 1] = (unsigned)w2 | ((unsigned)w3 << 16);
                }
            }
        }
    }
    __syncthreads();   // b3 (all Xb reads + Q writes done)

    // ---------------- ph4: K -> R2 (over Xb) ----------------
    {
        #pragma unroll
        for (int mt = 0; mt < 2; ++mt) {
            #pragma unroll
            for (int nt = 0; nt < 4; ++nt) {
                int co = (q << 6) + (nt << 4) + lrow;
                #pragma unroll
                for (int r = 0; r < 4; ++r) {
                    int t = (th << 5) + (mt << 4) + (kg << 2) + r;
                    u16 val = (u16)(kpk[(mt * 4 + nt) * 2 + (r >> 1)] >> ((r & 1) * 16));
                    *(u16*)(R2 + swzA(t, co << 1)) = val;
                }
            }
        }
    }
    __syncthreads();   // b4

    // ---------------- ph5: S = Q_h K_h^T, softmax -> ppk regs ----------------
    unsigned ppk[16];
    {
        const int h = q;
        f32x4 s[2][4] = {};
        #pragma unroll
        for (int kk = 0; kk < 2; ++kk) {
            int c0 = (h << 6) + (kk << 5) + (kg << 3);
            bf16x8 a0 = *(const bf16x8*)(R1 + swzA((th << 5) + lrow,      c0 << 1));
            bf16x8 a1 = *(const bf16x8*)(R1 + swzA((th << 5) + 16 + lrow, c0 << 1));
            #pragma unroll
            for (int nt = 0; nt < 4; ++nt) {
                bf16x8 kb = *(const bf16x8*)(R2 + swzA((nt << 4) + lrow, c0 << 1));
                s[0][nt] = MFMA16(a0, kb, s[0][nt]);
                s[1][nt] = MFMA16(a1, kb, s[1][nt]);
            }
        }
        const float CS = 0.125f * 1.44269504f;
        #pragma unroll
        for (int mt = 0; mt < 2; ++mt) {
            #pragma unroll
            for (int r = 0; r < 4; ++r) {
                float mx = fmaxf(fmaxf(s[mt][0][r], s[mt][1][r]),
                                 fmaxf(s[mt][2][r], s[mt][3][r]));
                mx = fmaxf(mx, __shfl_xor(mx, 1));
                mx = fmaxf(mx, __shfl_xor(mx, 2));
                mx = fmaxf(mx, __shfl_xor(mx, 4));
                mx = fmaxf(mx, __shfl_xor(mx, 8));
                float p0 = exp2f((s[mt][0][r] - mx) * CS);
                float p1 = exp2f((s[mt][1][r] - mx) * CS);
                float p2 = exp2f((s[mt][2][r] - mx) * CS);
                float p3 = exp2f((s[mt][3][r] - mx) * CS);
                float sm = (p0 + p1) + (p2 + p3);
                sm += __shfl_xor(sm, 1);
                sm += __shfl_xor(sm, 2);
                sm += __shfl_xor(sm, 4);
                sm += __shfl_xor(sm, 8);
                float inv = 1.0f / sm;
                p0 *= inv; p1 *= inv; p2 *= inv; p3 *= inv;
                ppk[(mt * 4 + r) * 2 + 0] = (unsigned)bfbits(p0) | ((unsigned)bfbits(p1) << 16);
                ppk[(mt * 4 + r) * 2 + 1] = (unsigned)bfbits(p2) | ((unsigned)bfbits(p3) << 16);
            }
        }
    }
    __syncthreads();   // b5 (all Q/K reads done)

    // ---------------- ph6: P -> R2 ([4][64][64]) ; V^T -> R1 ([256][64]) ----------------
    {
        const int h = q;
        #pragma unroll
        for (int mt = 0; mt < 2; ++mt) {
            #pragma unroll
            for (int r = 0; r < 4; ++r) {
                int i = (th << 5) + (mt << 4) + (kg << 2) + r;
                #pragma unroll
                for (int nt = 0; nt < 4; ++nt) {
                    u16 val = (u16)(ppk[(mt * 4 + r) * 2 + (nt >> 1)] >> ((nt & 1) * 16));
                    *(u16*)(R2 + (h << 13) + swzB(i, ((nt << 4) + lrow) << 1)) = val;
                }
            }
        }
        #pragma unroll
        for (int mt = 0; mt < 4; ++mt) {
            #pragma unroll
            for (int r = 0; r < 4; ++r) {
                int vc = (q << 6) + (mt << 4) + (kg << 2) + r;
                #pragma unroll
                for (int nt = 0; nt < 2; ++nt) {
                    int t = (th << 5) + (nt << 4) + lrow;
                    u16 val = (u16)(vpk[(mt * 2 + nt) * 2 + (r >> 1)] >> ((r & 1) * 16));
                    *(u16*)(R1 + swzB(vc, t << 1)) = val;
                }
            }
        }
    }
    __syncthreads();   // b6

    // ---------------- ph7: O = P * V (regs) ----------------
    f32x4 o[2][4] = {};
    {
        const int h = q;
        #pragma unroll
        for (int kk = 0; kk < 2; ++kk) {
            int j0 = (kk << 5) + (kg << 3);
            bf16x8 a0 = *(const bf16x8*)(R2 + (h << 13) + swzB((th << 5) + lrow,      j0 << 1));
            bf16x8 a1 = *(const bf16x8*)(R2 + (h << 13) + swzB((th << 5) + 16 + lrow, j0 << 1));
            #pragma unroll
            for (int dt = 0; dt < 4; ++dt) {
                bf16x8 vb = *(const bf16x8*)(R1 + swzB((h << 6) + (dt << 4) + lrow, j0 << 1));
                o[0][dt] = MFMA16(a0, vb, o[0][dt]);
                o[1][dt] = MFMA16(a1, vb, o[1][dt]);
            }
        }
    }
    __syncthreads();   // b7 (all P/V reads done)

    // ---------------- ph8: O -> R1 ([64][256]) ----------------
    {
        const int h = q;
        #pragma unroll
        for (int mt = 0; mt < 2; ++mt) {
            #pragma unroll
            for (int dt = 0; dt < 4; ++dt) {
                #pragma unroll
                for (int r = 0; r < 4; ++r) {
                    int t = (th << 5) + (mt << 4) + (kg << 2) + r;
                    int c = (h << 6) + (dt << 4) + lrow;
                    *(__bf16*)(R1 + swzA(t, c << 1)) = (__bf16)o[mt][dt][r];
                }
            }
        }
    }
    __syncthreads();   // b8

    // ---------------- ph9: Out^T = Wo * O^T + bo -> global ----------------
    {
        f32x4 acc[4][2] = {};
        #pragma unroll
        for (int kk = 0; kk < 8; ++kk) {
            int k0 = (kk << 5) + (kg << 3);
            bf16x8 b0 = *(const bf16x8*)(R1 + swzA((th << 5) + lrow,      k0 << 1));
            bf16x8 b1 = *(const bf16x8*)(R1 + swzA((th << 5) + 16 + lrow, k0 << 1));
            #pragma unroll
            for (int mt = 0; mt < 4; ++mt) {
                bf16x8 aw = loadWP(WPo, q, kk, mt, l);
                acc[mt][0] = MFMA16(aw, b0, acc[mt][0]);
                acc[mt][1] = MFMA16(aw, b1, acc[mt][1]);
            }
        }
        #pragma unroll
        for (int mt = 0; mt < 4; ++mt) {
            #pragma unroll
            for (int r = 0; r < 4; ++r) {
                int c = (q << 6) + (mt << 4) + (kg << 2) + r;
                float bi = bo[c];
                #pragma unroll
                for (int nt = 0; nt < 2; ++nt) {
                    int t = (th << 5) + (nt << 4) + lrow;
                    int y = ybase + (t >> 3);
                    int x = xbase + (t & 7);
                    size_t off = (((size_t)b * 256 + c) * 128 + y) * 128 + x;
                    outg[off] = acc[mt][nt][r] + bi;
                }
            }
        }
    }

    // ---------------- tail: attn copy (P in R2, synced at b6) — no barrier after ----------------
    {
        #pragma unroll
        for (int it = 0; it < 4; ++it) {
            int idx = (it << 9) + tid;                 // 0..2047
            int h2 = idx >> 9;
            int i2 = (idx >> 3) & 63;
            int jb = (idx & 7) << 3;
            u16x8 v = *(const u16x8*)(R2 + (h2 << 13) + swzB(i2, jb << 1));
            float* dp = attng + ((((size_t)(win << 2) + h2) << 6) + i2) * 64 + jb;
            f32x4 o0, o1;
            #pragma unroll
            for (int e = 0; e < 4; ++e) {
                union { unsigned u; float f; } c0; c0.u = (unsigned)v[e] << 16;
                union { unsigned u; float f; } c1; c1.u = (unsigned)v[4 + e] << 16;
                o0[e] = c0.f; o1[e] = c1.f;
            }
            *(f32x4*)dp = o0;
            *(f32x4*)(dp + 4) = o1;
        }
    }
}

extern "C" void kernel_launch(void* const* d_in, const int* in_sizes, int n_in,
                              void* d_out, int out_size, void* d_ws, size_t ws_size,
                              hipStream_t stream) {
    (void)in_sizes; (void)n_in; (void)ws_size; (void)out_size;
    const float* fa = (const float*)d_in[0];
    const float* fb = (const float*)d_in[1];
    const float* Wq = (const float*)d_in[2];
    const float* bq = (const float*)d_in[3];
    const float* Wk = (const float*)d_in[4];
    const float* bk = (const float*)d_in[5];
    const float* Wv = (const float*)d_in[6];
    const float* bv = (const float*)d_in[7];
    const float* Wo = (const float*)d_in[8];
    const float* bo = (const float*)d_in[9];
    float* outg  = (float*)d_out;
    float* attng = outg + (size_t)8 * 256 * 128 * 128;   // out first, then attn (fp32)

    __bf16* pk = (__bf16*)d_ws;                          // 4 x 128KB packed weights
    const __bf16* WPq = pk;
    const __bf16* WPk = pk + 65536;
    const __bf16* WPv = pk + 131072;
    const __bf16* WPo = pk + 196608;

    pack_weights<<<dim3(128), dim3(256), 0, stream>>>(Wq, Wk, Wv, Wo, pk);
    wca_fused<<<dim3(2048), dim3(512), 0, stream>>>(
        fa, fb, WPq, bq, WPk, bk, WPv, bv, WPo, bo, outg, attng);
}

// Round 23
// 268.654 us; speedup vs baseline: 6.1405x; 1.1456x over previous
//
#include <hip/hip_runtime.h>
#include <hip/hip_bf16.h>

// Fused window cross-attention, MI355X gfx950. fp32 in, fp32 out.
// Round 23: r22 base (308us clean) + 32-col-group wave mapping in the four
// weight-GEMM phases (Q/K/V/O): wave w owns cols w*32..w*32+31 for ALL 64
// tokens (was 64-col x token-half, with wave PAIRS loading identical weight
// fragments). Halves per-block weight L1/L2 traffic (1MB -> 512KB) and VMEM
// issue count. S/softmax and PV phases keep the head-based mapping.
// R1(32KB): Xa -> Q -> V^T -> O ; R2(32KB): Xb -> K -> P (P live to end).

typedef __bf16 bf16x8 __attribute__((ext_vector_type(8)));
typedef float f32x4 __attribute__((ext_vector_type(4)));
typedef unsigned short u16;
typedef unsigned short u16x8 __attribute__((ext_vector_type(8)));

#define MFMA16(A, B, C) __builtin_amdgcn_mfma_f32_16x16x32_bf16((A), (B), (C), 0, 0, 0)

__device__ __forceinline__ int swzA(int t, int byteInRow) {        // rows of 512B ([64][256] bf16)
    return (t << 9) + (byteInRow ^ ((((t & 7) ^ (t >> 3)) & 7) << 4));
}
__device__ __forceinline__ int swzB(int r, int byteInRow) {        // rows of 128B ([*][64] bf16)
    return (r << 7) + (byteInRow ^ ((((r & 7) ^ (r >> 3)) & 7) << 4));
}
__device__ __forceinline__ u16 bfbits(float x) {
    __bf16 h = (__bf16)x;
    return *(u16*)&h;
}

// ---------------- prep: pack weights into fragment order ----------------
__global__ __launch_bounds__(256) void pack_weights(
    const float* __restrict__ Wq, const float* __restrict__ Wk,
    const float* __restrict__ Wv, const float* __restrict__ Wo,
    __bf16* __restrict__ pk)
{
    int gid = blockIdx.x * 256 + threadIdx.x;   // 0..32767
    int m = gid >> 13;
    int f = gid & 8191;
    const float* W = (m == 0) ? Wq : (m == 1) ? Wk : (m == 2) ? Wv : Wo;
    int q  = f >> 11;
    int kk = (f >> 8) & 7;
    int t16 = (f >> 6) & 3;
    int l  = f & 63;
    int row = (q << 6) + (t16 << 4) + (l & 15);
    int col = (kk << 5) + ((l >> 4) << 3);
    const float* s = W + row * 256 + col;
    f32x4 a = *(const f32x4*)s;
    f32x4 b = *(const f32x4*)(s + 4);
    bf16x8 r;
    r[0] = (__bf16)a[0]; r[1] = (__bf16)a[1]; r[2] = (__bf16)a[2]; r[3] = (__bf16)a[3];
    r[4] = (__bf16)b[0]; r[5] = (__bf16)b[1]; r[6] = (__bf16)b[2]; r[7] = (__bf16)b[3];
    *(bf16x8*)(pk + (size_t)gid * 8) = r;
}

__device__ __forceinline__ bf16x8 loadWP(const __bf16* __restrict__ pk,
                                         int q, int kk, int t16, int l) {
    return *(const bf16x8*)(pk + ((((q << 3) + kk) << 2) + t16) * 512 + (l << 3));
}

__global__ __launch_bounds__(512, 2) void wca_fused(
    const float* __restrict__ fa, const float* __restrict__ fb,
    const __bf16* __restrict__ WPq, const float* __restrict__ bq,
    const __bf16* __restrict__ WPk, const float* __restrict__ bk,
    const __bf16* __restrict__ WPv, const float* __restrict__ bv,
    const __bf16* __restrict__ WPo, const float* __restrict__ bo,
    float* __restrict__ outg, float* __restrict__ attng)
{
    __shared__ __attribute__((aligned(16))) char S[65536];
    char* const R1 = S;              // Xa -> Q [64][256] -> V^T [256][64] -> O [64][256]
    char* const R2 = S + 32768;      // Xb -> K [64][256] -> P [4][64][64] (P live to end)

    const int tid  = threadIdx.x;
    const int l    = tid & 63;
    const int wid  = tid >> 6;      // wave 0..7
    const int lrow = l & 15;
    const int kg   = l >> 4;
    // weight-GEMM mapping: wave owns 32 cols (2 x 16-col tiles), all 64 tokens
    const int cq   = wid >> 1;      // 64-col group for packed weights
    const int ct   = (wid & 1) << 1;// 16-col tile base within group (0 or 2)
    // attention mapping (ph5/ph7): head x token-half
    const int q    = wid & 3;
    const int th   = wid >> 2;

    const int wgid = blockIdx.x;
    const int win  = ((wgid & 7) << 8) | (wgid >> 3);
    const int b    = win >> 8;
    const int wy   = (win >> 4) & 15;
    const int wx   = win & 15;
    const int ybase = wy << 3, xbase = wx << 3;

    // ---------------- ph1: stage Xa -> R1, Xb -> R2 ----------------
    {
        #pragma unroll
        for (int f = 0; f < 2; ++f) {
            const float* src = f ? fb : fa;
            char* dst = f ? R2 : R1;
            #pragma unroll
            for (int it = 0; it < 4; ++it) {
                int idx = (it << 9) + tid;          // 0..2047 = (c, ty)
                int c  = idx >> 3;
                int ty = idx & 7;
                const float* gp = src + ((((size_t)b * 256 + c) * 128 + ybase + ty) * 128 + xbase);
                f32x4 v0 = *(const f32x4*)gp;
                f32x4 v1 = *(const f32x4*)(gp + 4);
                #pragma unroll
                for (int tx = 0; tx < 4; ++tx) {
                    *(__bf16*)(dst + swzA((ty << 3) + tx,     c << 1)) = (__bf16)v0[tx];
                    *(__bf16*)(dst + swzA((ty << 3) + 4 + tx, c << 1)) = (__bf16)v1[tx];
                }
            }
        }
    }
    __syncthreads();   // b1

    // ---------------- ph2: Q = Xa*Wq^T (regs, 32-col mapping) ----------------
    f32x4 qacc[4][2] = {};
    {
        #pragma unroll
        for (int kk = 0; kk < 8; ++kk) {
            int c0 = (kk << 5) + (kg << 3);
            bf16x8 a0 = *(const bf16x8*)(R1 + swzA(lrow,      c0 << 1));
            bf16x8 a1 = *(const bf16x8*)(R1 + swzA(16 + lrow, c0 << 1));
            bf16x8 a2 = *(const bf16x8*)(R1 + swzA(32 + lrow, c0 << 1));
            bf16x8 a3 = *(const bf16x8*)(R1 + swzA(48 + lrow, c0 << 1));
            #pragma unroll
            for (int nt = 0; nt < 2; ++nt) {
                bf16x8 bb = loadWP(WPq, cq, kk, ct + nt, l);
                qacc[0][nt] = MFMA16(a0, bb, qacc[0][nt]);
                qacc[1][nt] = MFMA16(a1, bb, qacc[1][nt]);
                qacc[2][nt] = MFMA16(a2, bb, qacc[2][nt]);
                qacc[3][nt] = MFMA16(a3, bb, qacc[3][nt]);
            }
        }
    }
    __syncthreads();   // b2 (all Xa reads done)

    // ---------------- ph3: Q -> R1 ; K,V^T = f(Xb) -> regs (bf16-packed) ----------------
    unsigned kpk[16], vpk[16];
    {
        // Q write (over Xa)
        #pragma unroll
        for (int mt = 0; mt < 4; ++mt) {
            #pragma unroll
            for (int nt = 0; nt < 2; ++nt) {
                int co = (cq << 6) + ((ct + nt) << 4) + lrow;
                float bi = bq[co];
                #pragma unroll
                for (int r = 0; r < 4; ++r) {
                    int t = (mt << 4) + (kg << 2) + r;
                    *(__bf16*)(R1 + swzA(t, co << 1)) = (__bf16)(qacc[mt][nt][r] + bi);
                }
            }
        }
        // K projection -> kacc -> kpk
        {
            f32x4 kacc[4][2] = {};
            #pragma unroll
            for (int kk = 0; kk < 8; ++kk) {
                int c0 = (kk << 5) + (kg << 3);
                bf16x8 a0 = *(const bf16x8*)(R2 + swzA(lrow,      c0 << 1));
                bf16x8 a1 = *(const bf16x8*)(R2 + swzA(16 + lrow, c0 << 1));
                bf16x8 a2 = *(const bf16x8*)(R2 + swzA(32 + lrow, c0 << 1));
                bf16x8 a3 = *(const bf16x8*)(R2 + swzA(48 + lrow, c0 << 1));
                #pragma unroll
                for (int nt = 0; nt < 2; ++nt) {
                    bf16x8 bb = loadWP(WPk, cq, kk, ct + nt, l);
                    kacc[0][nt] = MFMA16(a0, bb, kacc[0][nt]);
                    kacc[1][nt] = MFMA16(a1, bb, kacc[1][nt]);
                    kacc[2][nt] = MFMA16(a2, bb, kacc[2][nt]);
                    kacc[3][nt] = MFMA16(a3, bb, kacc[3][nt]);
                }
            }
            #pragma unroll
            for (int mt = 0; mt < 4; ++mt) {
                #pragma unroll
                for (int nt = 0; nt < 2; ++nt) {
                    float bi = bk[(cq << 6) + ((ct + nt) << 4) + lrow];
                    kpk[(mt * 2 + nt) * 2 + 0] =
                        (unsigned)bfbits(kacc[mt][nt][0] + bi) |
                        ((unsigned)bfbits(kacc[mt][nt][1] + bi) << 16);
                    kpk[(mt * 2 + nt) * 2 + 1] =
                        (unsigned)bfbits(kacc[mt][nt][2] + bi) |
                        ((unsigned)bfbits(kacc[mt][nt][3] + bi) << 16);
                }
            }
        }
        // V^T projection -> vacc -> vpk (A = weights/channels, B = Xb tokens)
        {
            f32x4 vacc[2][4] = {};
            #pragma unroll
            for (int kk = 0; kk < 8; ++kk) {
                int c0 = (kk << 5) + (kg << 3);
                bf16x8 b0 = *(const bf16x8*)(R2 + swzA(lrow,      c0 << 1));
                bf16x8 b1 = *(const bf16x8*)(R2 + swzA(16 + lrow, c0 << 1));
                bf16x8 b2 = *(const bf16x8*)(R2 + swzA(32 + lrow, c0 << 1));
                bf16x8 b3 = *(const bf16x8*)(R2 + swzA(48 + lrow, c0 << 1));
                #pragma unroll
                for (int mt = 0; mt < 2; ++mt) {
                    bf16x8 aw = loadWP(WPv, cq, kk, ct + mt, l);
                    vacc[mt][0] = MFMA16(aw, b0, vacc[mt][0]);
                    vacc[mt][1] = MFMA16(aw, b1, vacc[mt][1]);
                    vacc[mt][2] = MFMA16(aw, b2, vacc[mt][2]);
                    vacc[mt][3] = MFMA16(aw, b3, vacc[mt][3]);
                }
            }
            #pragma unroll
            for (int mt = 0; mt < 2; ++mt) {
                #pragma unroll
                for (int nt = 0; nt < 4; ++nt) {
                    int vcb = (cq << 6) + ((ct + mt) << 4) + (kg << 2);
                    u16 w0 = bfbits(vacc[mt][nt][0] + bv[vcb + 0]);
                    u16 w1 = bfbits(vacc[mt][nt][1] + bv[vcb + 1]);
                    u16 w2 = bfbits(vacc[mt][nt][2] + bv[vcb + 2]);
                    u16 w3 = bfbits(vacc[mt][nt][3] + bv[vcb + 3]);
                    vpk[(mt * 4 + nt) * 2 + 0] = (unsigned)w0 | ((unsigned)w1 << 16);
                    vpk[(mt * 4 + nt) * 2 + 1] = (unsigned)w2 | ((unsigned)w3 << 16);
                }
            }
        }
    }
    __syncthreads();   // b3 (all Xb reads + Q writes done)

    // ---------------- ph4: K -> R2 (over Xb) ----------------
    {
        #pragma unroll
        for (int mt = 0; mt < 4; ++mt) {
            #pragma unroll
            for (int nt = 0; nt < 2; ++nt) {
                int co = (cq << 6) + ((ct + nt) << 4) + lrow;
                #pragma unroll
                for (int r = 0; r < 4; ++r) {
                    int t = (mt << 4) + (kg << 2) + r;
                    u16 val = (u16)(kpk[(mt * 2 + nt) * 2 + (r >> 1)] >> ((r & 1) * 16));
                    *(u16*)(R2 + swzA(t, co << 1)) = val;
                }
            }
        }
    }
    __syncthreads();   // b4

    // ---------------- ph5: S = Q_h K_h^T, softmax -> ppk regs (head mapping) ----------------
    unsigned ppk[16];
    {
        const int h = q;
        f32x4 s[2][4] = {};
        #pragma unroll
        for (int kk = 0; kk < 2; ++kk) {
            int c0 = (h << 6) + (kk << 5) + (kg << 3);
            bf16x8 a0 = *(const bf16x8*)(R1 + swzA((th << 5) + lrow,      c0 << 1));
            bf16x8 a1 = *(const bf16x8*)(R1 + swzA((th << 5) + 16 + lrow, c0 << 1));
            #pragma unroll
            for (int nt = 0; nt < 4; ++nt) {
                bf16x8 kb = *(const bf16x8*)(R2 + swzA((nt << 4) + lrow, c0 << 1));
                s[0][nt] = MFMA16(a0, kb, s[0][nt]);
                s[1][nt] = MFMA16(a1, kb, s[1][nt]);
            }
        }
        const float CS = 0.125f * 1.44269504f;
        #pragma unroll
        for (int mt = 0; mt < 2; ++mt) {
            #pragma unroll
            for (int r = 0; r < 4; ++r) {
                float mx = fmaxf(fmaxf(s[mt][0][r], s[mt][1][r]),
                                 fmaxf(s[mt][2][r], s[mt][3][r]));
                mx = fmaxf(mx, __shfl_xor(mx, 1));
                mx = fmaxf(mx, __shfl_xor(mx, 2));
                mx = fmaxf(mx, __shfl_xor(mx, 4));
                mx = fmaxf(mx, __shfl_xor(mx, 8));
                float p0 = exp2f((s[mt][0][r] - mx) * CS);
                float p1 = exp2f((s[mt][1][r] - mx) * CS);
                float p2 = exp2f((s[mt][2][r] - mx) * CS);
                float p3 = exp2f((s[mt][3][r] - mx) * CS);
                float sm = (p0 + p1) + (p2 + p3);
                sm += __shfl_xor(sm, 1);
                sm += __shfl_xor(sm, 2);
                sm += __shfl_xor(sm, 4);
                sm += __shfl_xor(sm, 8);
                float inv = 1.0f / sm;
                p0 *= inv; p1 *= inv; p2 *= inv; p3 *= inv;
                ppk[(mt * 4 + r) * 2 + 0] = (unsigned)bfbits(p0) | ((unsigned)bfbits(p1) << 16);
                ppk[(mt * 4 + r) * 2 + 1] = (unsigned)bfbits(p2) | ((unsigned)bfbits(p3) << 16);
            }
        }
    }
    __syncthreads();   // b5 (all Q/K reads done)

    // ---------------- ph6: P -> R2 ([4][64][64]) ; V^T -> R1 ([256][64]) ----------------
    {
        const int h = q;
        #pragma unroll
        for (int mt = 0; mt < 2; ++mt) {
            #pragma unroll
            for (int r = 0; r < 4; ++r) {
                int i = (th << 5) + (mt << 4) + (kg << 2) + r;
                #pragma unroll
                for (int nt = 0; nt < 4; ++nt) {
                    u16 val = (u16)(ppk[(mt * 4 + r) * 2 + (nt >> 1)] >> ((nt & 1) * 16));
                    *(u16*)(R2 + (h << 13) + swzB(i, ((nt << 4) + lrow) << 1)) = val;
                }
            }
        }
        #pragma unroll
        for (int mt = 0; mt < 2; ++mt) {
            #pragma unroll
            for (int nt = 0; nt < 4; ++nt) {
                #pragma unroll
                for (int r = 0; r < 4; ++r) {
                    int vc = (cq << 6) + ((ct + mt) << 4) + (kg << 2) + r;
                    int t  = (nt << 4) + lrow;
                    u16 val = (u16)(vpk[(mt * 4 + nt) * 2 + (r >> 1)] >> ((r & 1) * 16));
                    *(u16*)(R1 + swzB(vc, t << 1)) = val;
                }
            }
        }
    }
    __syncthreads();   // b6

    // ---------------- ph7: O = P * V (regs, head mapping) ----------------
    f32x4 o[2][4] = {};
    {
        const int h = q;
        #pragma unroll
        for (int kk = 0; kk < 2; ++kk) {
            int j0 = (kk << 5) + (kg << 3);
            bf16x8 a0 = *(const bf16x8*)(R2 + (h << 13) + swzB((th << 5) + lrow,      j0 << 1));
            bf16x8 a1 = *(const bf16x8*)(R2 + (h << 13) + swzB((th << 5) + 16 + lrow, j0 << 1));
            #pragma unroll
            for (int dt = 0; dt < 4; ++dt) {
                bf16x8 vb = *(const bf16x8*)(R1 + swzB((h << 6) + (dt << 4) + lrow, j0 << 1));
                o[0][dt] = MFMA16(a0, vb, o[0][dt]);
                o[1][dt] = MFMA16(a1, vb, o[1][dt]);
            }
        }
    }
    __syncthreads();   // b7 (all P/V reads done)

    // ---------------- ph8: O -> R1 ([64][256]) ----------------
    {
        const int h = q;
        #pragma unroll
        for (int mt = 0; mt < 2; ++mt) {
            #pragma unroll
            for (int dt = 0; dt < 4; ++dt) {
                #pragma unroll
                for (int r = 0; r < 4; ++r) {
                    int t = (th << 5) + (mt << 4) + (kg << 2) + r;
                    int c = (h << 6) + (dt << 4) + lrow;
                    *(__bf16*)(R1 + swzA(t, c << 1)) = (__bf16)o[mt][dt][r];
                }
            }
        }
    }
    __syncthreads();   // b8

    // ---------------- ph9: Out^T = Wo * O^T + bo -> global (32-col mapping) ----------------
    {
        f32x4 acc[2][4] = {};
        #pragma unroll
        for (int kk = 0; kk < 8; ++kk) {
            int k0 = (kk << 5) + (kg << 3);
            bf16x8 b0 = *(const bf16x8*)(R1 + swzA(lrow,      k0 << 1));
            bf16x8 b1 = *(const bf16x8*)(R1 + swzA(16 + lrow, k0 << 1));
            bf16x8 b2 = *(const bf16x8*)(R1 + swzA(32 + lrow, k0 << 1));
            bf16x8 b3 = *(const bf16x8*)(R1 + swzA(48 + lrow, k0 << 1));
            #pragma unroll
            for (int mt = 0; mt < 2; ++mt) {
                bf16x8 aw = loadWP(WPo, cq, kk, ct + mt, l);
                acc[mt][0] = MFMA16(aw, b0, acc[mt][0]);
                acc[mt][1] = MFMA16(aw, b1, acc[mt][1]);
                acc[mt][2] = MFMA16(aw, b2, acc[mt][2]);
                acc[mt][3] = MFMA16(aw, b3, acc[mt][3]);
            }
        }
        #pragma unroll
        for (int mt = 0; mt < 2; ++mt) {
            #pragma unroll
            for (int r = 0; r < 4; ++r) {
                int c = (cq << 6) + ((ct + mt) << 4) + (kg << 2) + r;
                float bi = bo[c];
                #pragma unroll
                for (int nt = 0; nt < 4; ++nt) {
                    int t = (nt << 4) + lrow;
                    int y = ybase + (t >> 3);
                    int x = xbase + (t & 7);
                    size_t off = (((size_t)b * 256 + c) * 128 + y) * 128 + x;
                    outg[off] = acc[mt][nt][r] + bi;
                }
            }
        }
    }

    // ---------------- tail: attn copy (P in R2, synced at b6) — no barrier after ----------------
    {
        #pragma unroll
        for (int it = 0; it < 4; ++it) {
            int idx = (it << 9) + tid;                 // 0..2047
            int h2 = idx >> 9;
            int i2 = (idx >> 3) & 63;
            int jb = (idx & 7) << 3;
            u16x8 v = *(const u16x8*)(R2 + (h2 << 13) + swzB(i2, jb << 1));
            float* dp = attng + ((((size_t)(win << 2) + h2) << 6) + i2) * 64 + jb;
            f32x4 o0, o1;
            #pragma unroll
            for (int e = 0; e < 4; ++e) {
                union { unsigned u; float f; } c0; c0.u = (unsigned)v[e] << 16;
                union { unsigned u; float f; } c1; c1.u = (unsigned)v[4 + e] << 16;
                o0[e] = c0.f; o1[e] = c1.f;
            }
            *(f32x4*)dp = o0;
            *(f32x4*)(dp + 4) = o1;
        }
    }
}

extern "C" void kernel_launch(void* const* d_in, const int* in_sizes, int n_in,
                              void* d_out, int out_size, void* d_ws, size_t ws_size,
                              hipStream_t stream) {
    (void)in_sizes; (void)n_in; (void)ws_size; (void)out_size;
    const float* fa = (const float*)d_in[0];
    const float* fb = (const float*)d_in[1];
    const float* Wq = (const float*)d_in[2];
    const float* bq = (const float*)d_in[3];
    const float* Wk = (const float*)d_in[4];
    const float* bk = (const float*)d_in[5];
    const float* Wv = (const float*)d_in[6];
    const float* bv = (const float*)d_in[7];
    const float* Wo = (const float*)d_in[8];
    const float* bo = (const float*)d_in[9];
    float* outg  = (float*)d_out;
    float* attng = outg + (size_t)8 * 256 * 128 * 128;   // out first, then attn (fp32)

    __bf16* pk = (__bf16*)d_ws;                          // 4 x 128KB packed weights
    const __bf16* WPq = pk;
    const __bf16* WPk = pk + 65536;
    const __bf16* WPv = pk + 131072;
    const __bf16* WPo = pk + 196608;

    pack_weights<<<dim3(128), dim3(256), 0, stream>>>(Wq, Wk, Wv, Wo, pk);
    wca_fused<<<dim3(2048), dim3(512), 0, stream>>>(
        fa, fb, WPq, bq, WPk, bk, WPv, bv, WPo, bo, outg, attng);
}